// Round 1
// baseline (513.674 us; speedup 1.0000x reference)
//
#include <hip/hip_runtime.h>

// RuleFilter: out[0] = logits[0]; out[i] = logits[i] * mask_table[argmax(out[i-1])]
// logits: (L=128, N=4096, V=128) fp32, mask_table: (128,128) fp32 {0,1}.
// One wave per sequence n; lane holds vocab elems {2*lane, 2*lane+1}.
// Mask table compressed to a 2 KB LDS bitmask per block.

constexpr int V = 128;
constexpr int L = 128;
constexpr int N = 4096;

__global__ __launch_bounds__(256) void rule_filter_kernel(
    const float* __restrict__ logits,      // (L, N, V)
    const float* __restrict__ mask_table,  // (V, V)
    float* __restrict__ out)               // (L, N, V)
{
    // --- build bitmask: mbits[p*4 + w] bit b == (mask_table[p][w*32+b] != 0) ---
    __shared__ unsigned int mbits[V * 4];
    for (int w = threadIdx.x; w < V * 4; w += 256) {
        const int row  = w >> 2;
        const int word = w & 3;
        const float* srcm = mask_table + row * V + word * 32;
        unsigned int bits = 0u;
#pragma unroll
        for (int k = 0; k < 32; ++k)
            bits |= (srcm[k] != 0.0f) ? (1u << k) : 0u;
        mbits[w] = bits;
    }
    __syncthreads();

    const int wave = threadIdx.x >> 6;   // 0..3
    const int lane = threadIdx.x & 63;   // 0..63
    const int n    = (blockIdx.x << 2) + wave;   // sequence index, < 4096

    const size_t base    = (size_t)n * V + (size_t)(lane * 2);
    const size_t rstride = (size_t)N * V;       // floats per L-row

    // both of this lane's mask bits live in word (lane>>4) at bit (lane&15)*2
    const int mword  = lane >> 4;
    const int mshift = (lane & 15) * 2;

    auto ld = [&](int i) -> float2 {
        return *(const float2*)(logits + (size_t)i * rstride + base);
    };
    auto st = [&](int i, float2 v) {
        *(float2*)(out + (size_t)i * rstride + base) = v;
    };

    // argmax over the 128 values held by this wave; ties -> lowest index
    auto wave_argmax = [&](float2 f) -> int {
        float bv; int bi;
        if (f.y > f.x) { bv = f.y; bi = lane * 2 + 1; }
        else           { bv = f.x; bi = lane * 2;     }
#pragma unroll
        for (int off = 32; off >= 1; off >>= 1) {
            float ov = __shfl_xor(bv, off);
            int   oi = __shfl_xor(bi, off);
            if (ov > bv || (ov == bv && oi < bi)) { bv = ov; bi = oi; }
        }
        return bi;   // wave-uniform
    };

    constexpr int D = 4;   // prefetch depth
    float2 buf[D];
#pragma unroll
    for (int j = 0; j < D; ++j) buf[j] = ld(j);

    // row 0 passes through unfiltered
    st(0, buf[0]);
    int prev = wave_argmax(buf[0]);

#pragma unroll 4
    for (int i = 1; i < L; ++i) {
        float2 c = buf[i & (D - 1)];
        // prefetch row i+D-1 (clamped; redundant re-loads of last row are harmless)
        const int pf = (i + D - 1 < L) ? (i + D - 1) : (L - 1);
        buf[pf & (D - 1)] = ld(pf);

        const unsigned int word = mbits[prev * 4 + mword];
        const unsigned int b    = (word >> mshift) & 3u;
        float2 f;
        f.x = (b & 1u) ? c.x : 0.0f;
        f.y = (b & 2u) ? c.y : 0.0f;

        st(i, f);
        prev = wave_argmax(f);
    }
}

extern "C" void kernel_launch(void* const* d_in, const int* in_sizes, int n_in,
                              void* d_out, int out_size, void* d_ws, size_t ws_size,
                              hipStream_t stream) {
    const float* logits     = (const float*)d_in[0];   // (L, N, V) fp32
    const float* mask_table = (const float*)d_in[1];   // (V, V) fp32
    float* out              = (float*)d_out;           // (L, N, V) fp32

    dim3 grid(N / 4);   // 4 sequences (waves) per 256-thread block
    dim3 block(256);
    rule_filter_kernel<<<grid, block, 0, stream>>>(logits, mask_table, out);
}

// Round 2
// 490.302 us; speedup vs baseline: 1.0477x; 1.0477x over previous
//
#include <hip/hip_runtime.h>
#include <string.h>

// RuleFilter: out[0] = logits[0]; out[i] = logits[i] * mask_table[argmax(out[i-1])]
// logits: (L=128, N=4096, V=128) fp32, mask_table: (128,128) fp32 {0,1}.
// One wave per sequence n; lane holds vocab elems {2*lane, 2*lane+1}.
// Chain kept entirely on VALU/SALU: DPP max-reduce + ballot argmax + VGPR mask table.

constexpr int V = 128;
constexpr int L = 128;
constexpr int N = 4096;

// Wave-wide max of x (all 64 lanes active), result broadcast to all lanes.
// Pure VALU: v_max_f32 with DPP row_shr/row_bcast, then readlane.
__device__ __forceinline__ float wave_max_dpp(float x) {
    int v = __float_as_int(x);
    const int ninf = __float_as_int(-__builtin_inff());
#define RF_STEP(ctrl)                                                          \
    {                                                                          \
        int s = __builtin_amdgcn_update_dpp(ninf, v, ctrl, 0xf, 0xf, false);   \
        v = __float_as_int(fmaxf(__int_as_float(v), __int_as_float(s)));       \
    }
    RF_STEP(0x111)  // row_shr:1
    RF_STEP(0x112)  // row_shr:2
    RF_STEP(0x114)  // row_shr:4
    RF_STEP(0x118)  // row_shr:8  -> lane 15 of each row16 has row max
    RF_STEP(0x142)  // row_bcast:15 -> lane31 = max(0..31), lane63 = max(32..63)
    RF_STEP(0x143)  // row_bcast:31 -> lane63 = max(all)
#undef RF_STEP
    return __int_as_float(__builtin_amdgcn_readlane(v, 63));
}

// argmax over the 128 values {f.x@2*lane, f.y@2*lane+1}; ties -> lowest index.
__device__ __forceinline__ int wave_argmax(float2 f) {
    const float bv = wave_max_dpp(fmaxf(f.x, f.y));
    unsigned long long b0 = __ballot(f.x == bv);
    unsigned long long b1 = __ballot(f.y == bv);
    int i0 = __ffsll(b0);  // 1-based, 0 if none
    int i1 = __ffsll(b1);
    int c0 = i0 ? (i0 - 1) * 2 : (1 << 30);
    int c1 = i1 ? (i1 - 1) * 2 + 1 : (1 << 30);
    return min(c0, c1);
}

// 8-way dynamic register select (j is wave-uniform; 7 cndmask/cselect ops).
__device__ __forceinline__ unsigned sel8(const unsigned* t, int j) {
    unsigned a0 = (j & 1) ? t[1] : t[0];
    unsigned a1 = (j & 1) ? t[3] : t[2];
    unsigned a2 = (j & 1) ? t[5] : t[4];
    unsigned a3 = (j & 1) ? t[7] : t[6];
    unsigned b0 = (j & 2) ? a1 : a0;
    unsigned b1 = (j & 2) ? a3 : a2;
    return (j & 4) ? b1 : b0;
}

__global__ __launch_bounds__(256) void rule_filter_kernel(
    const float* __restrict__ logits,      // (L, N, V)
    const float* __restrict__ mask_table,  // (V, V)
    float* __restrict__ out)               // (L, N, V)
{
    const int wave = threadIdx.x >> 6;  // 0..3
    const int lane = threadIdx.x & 63;  // 0..63
    const int n    = (blockIdx.x << 2) + wave;

    const size_t base    = (size_t)n * V + (size_t)(lane * 2);
    const size_t rstride = (size_t)N * V;

    // Per-lane mask table: tbl[j] bit(2r..2r+1) = mask_table[16j+r][2*lane .. 2*lane+1]
    // 8 VGPRs hold this lane's 2-bit field for all 128 possible prev tokens.
    unsigned tbl[8];
#pragma unroll 1
    for (int j = 0; j < 8; ++j) {
        unsigned acc = 0;
#pragma unroll
        for (int r = 0; r < 16; ++r) {
            const int p = j * 16 + r;
            float2 mv = *(const float2*)(mask_table + (size_t)p * V + lane * 2);
            acc |= ((mv.x != 0.0f ? 1u : 0u) | (mv.y != 0.0f ? 2u : 0u)) << (2 * r);
        }
        tbl[j] = acc;
    }

    auto ld = [&](int i) -> float2 {
        return *(const float2*)(logits + (size_t)i * rstride + base);
    };
    auto st = [&](int i, float2 v) {
        long long bits;
        memcpy(&bits, &v, 8);
        __builtin_nontemporal_store(bits, (long long*)(out + (size_t)i * rstride + base));
    };

    constexpr int D = 8;  // prefetch depth
    float2 buf[D];
#pragma unroll
    for (int k = 0; k < D; ++k) buf[k] = ld(k);

    // row 0 passes through unfiltered
    st(0, buf[0]);
    int prev = wave_argmax(buf[0]);

#pragma unroll 8
    for (int i = 1; i < L; ++i) {
        float2 c = buf[i & (D - 1)];
        const int pf = (i + D - 1 < L) ? (i + D - 1) : (L - 1);
        buf[pf & (D - 1)] = ld(pf);  // redundant tail re-loads are harmless

        const unsigned word  = sel8(tbl, prev >> 4);
        const unsigned fbits = (word >> ((prev & 15) * 2)) & 3u;
        float2 f;
        f.x = (fbits & 1u) ? c.x : 0.0f;
        f.y = (fbits & 2u) ? c.y : 0.0f;

        st(i, f);
        prev = wave_argmax(f);
    }
}

extern "C" void kernel_launch(void* const* d_in, const int* in_sizes, int n_in,
                              void* d_out, int out_size, void* d_ws, size_t ws_size,
                              hipStream_t stream) {
    const float* logits     = (const float*)d_in[0];  // (L, N, V) fp32
    const float* mask_table = (const float*)d_in[1];  // (V, V) fp32
    float* out              = (float*)d_out;          // (L, N, V) fp32

    dim3 grid(N / 4);  // 4 sequences (waves) per 256-thread block
    dim3 block(256);
    rule_filter_kernel<<<grid, block, 0, stream>>>(logits, mask_table, out);
}